// Round 4
// baseline (483.587 us; speedup 1.0000x reference)
//
#include <hip/hip_runtime.h>
#include <stdint.h>

#define BATCH 4
#define SEQ   2048
#define NHEAD 16
#define DHEAD 64
#define HID   1024

typedef __bf16 bf16x8 __attribute__((ext_vector_type(8)));
typedef float  f32x4  __attribute__((ext_vector_type(4)));

// ---------------------------------------------------------------------------
// dtype-polymorphic helpers: load 8 contiguous elements as bf16x8, scalar
// load as float, scalar store from float.
// ---------------------------------------------------------------------------
__device__ __forceinline__ bf16x8 load8(const __bf16* p) {
  return *(const bf16x8*)p;
}
__device__ __forceinline__ bf16x8 load8(const float* p) {
  const f32x4 a = ((const f32x4*)p)[0];
  const f32x4 b = ((const f32x4*)p)[1];
  bf16x8 r;
#pragma unroll
  for (int i = 0; i < 4; ++i) r[i] = (__bf16)a[i];
#pragma unroll
  for (int i = 0; i < 4; ++i) r[4 + i] = (__bf16)b[i];
  return r;
}

// ---------------------------------------------------------------------------
// Detector: classify d_in[0] words as f32 (mode 0) or packed bf16 (mode 1).
// f32 ~N(0,1): exponent field in ~[105,135]. bf16-pairs: the f32-exponent
// field holds the high-bf16's low exponent/mantissa bits -> {0..5, 240..255}.
// ---------------------------------------------------------------------------
__global__ void detect_kernel(const uint32_t* __restrict__ x, int* __restrict__ flag) {
  const int lane = threadIdx.x;   // 64 threads
  int sane = 0;
#pragma unroll
  for (int i = 0; i < 16; ++i) {
    const uint32_t w = x[lane * 16 + i];
    const uint32_t e = (w >> 23) & 0xFF;
    sane += (e >= 100 && e <= 140) ? 1 : 0;
  }
#pragma unroll
  for (int off = 1; off < 64; off <<= 1) sane += __shfl_xor(sane, off);
  if (lane == 0) *flag = (sane > 512) ? 0 : 1;
}

// ---------------------------------------------------------------------------
// Kernel 1: C = X @ W^T + b for n-group [n_base, n_base+GN). widx=blockIdx.z
// selects Q/K/V. Q (+RoPE) -> d_out[B,S,HID] (T-typed; Q storage until attn
// overwrites). K (+RoPE) -> Kws[B,GH,S,DH] bf16. V (operand-swapped MFMA)
// -> Vws[B,GH,DH,S] bf16.
// ---------------------------------------------------------------------------
#define ASTRIDE 40

template <typename T, int MODE>
__global__ __launch_bounds__(256, 2) void qkv_kernel(
    const int* __restrict__ flag,
    const T* __restrict__ x,
    const T* __restrict__ Wq, const T* __restrict__ bq,
    const T* __restrict__ Wk, const T* __restrict__ bk,
    const T* __restrict__ Wv, const T* __restrict__ bv,
    const T* __restrict__ sp,
    T* __restrict__ qout, __bf16* __restrict__ Kws, __bf16* __restrict__ Vws,
    int n_base, int GH)
{
  if (*flag != MODE) return;

  const int widx = blockIdx.z;
  const T* __restrict__ W    = (widx == 0) ? Wq : (widx == 1) ? Wk : Wv;
  const T* __restrict__ bias = (widx == 0) ? bq : (widx == 1) ? bk : bv;

  const int m0   = blockIdx.y * 128;
  const int n0   = n_base + blockIdx.x * 128;
  const int h0   = n_base >> 6;
  const int tid  = threadIdx.x;
  const int lane = tid & 63;
  const int quad = lane >> 4;
  const int l16  = lane & 15;
  const int wave = tid >> 6;
  const int wr   = wave >> 1, wc = wave & 1;

  __shared__ __align__(16) __bf16 As[128 * ASTRIDE];
  __shared__ __align__(16) __bf16 Bs[128 * ASTRIDE];

  const int srow = tid >> 2;        // 0..63 (+ i*64)
  const int scb  = tid & 3;         // col block 0..3

  f32x4 acc[4][4];
  const f32x4 z = {0.f, 0.f, 0.f, 0.f};
#pragma unroll
  for (int i = 0; i < 4; ++i)
#pragma unroll
    for (int j = 0; j < 4; ++j) acc[i][j] = z;

  bf16x8 areg[2], breg[2];
#pragma unroll
  for (int i = 0; i < 2; ++i) {
    areg[i] = load8(x + (size_t)(m0 + srow + i * 64) * HID + scb * 8);
    breg[i] = load8(W + (size_t)(n0 + srow + i * 64) * HID + scb * 8);
  }

  for (int k0 = 0; k0 < HID; k0 += 32) {
    __syncthreads();
#pragma unroll
    for (int i = 0; i < 2; ++i) {
      *(bf16x8*)(As + (srow + i * 64) * ASTRIDE + scb * 8) = areg[i];
      *(bf16x8*)(Bs + (srow + i * 64) * ASTRIDE + scb * 8) = breg[i];
    }
    __syncthreads();

    if (k0 + 32 < HID) {
#pragma unroll
      for (int i = 0; i < 2; ++i) {
        areg[i] = load8(x + (size_t)(m0 + srow + i * 64) * HID + (k0 + 32) + scb * 8);
        breg[i] = load8(W + (size_t)(n0 + srow + i * 64) * HID + (k0 + 32) + scb * 8);
      }
    }

    bf16x8 af[4], bfr[4];
#pragma unroll
    for (int mt = 0; mt < 4; ++mt)
      af[mt] = *(const bf16x8*)(As + (wr * 64 + mt * 16 + l16) * ASTRIDE + quad * 8);
#pragma unroll
    for (int nt = 0; nt < 4; ++nt)
      bfr[nt] = *(const bf16x8*)(Bs + (wc * 64 + nt * 16 + l16) * ASTRIDE + quad * 8);

    if (widx < 2) {
#pragma unroll
      for (int mt = 0; mt < 4; ++mt)
#pragma unroll
        for (int nt = 0; nt < 4; ++nt)
          acc[mt][nt] = __builtin_amdgcn_mfma_f32_16x16x32_bf16(af[mt], bfr[nt], acc[mt][nt], 0, 0, 0);
    } else {
      // swapped operands: D rows = W-rows (n), cols = X-rows (m) -> V^T
#pragma unroll
      for (int mt = 0; mt < 4; ++mt)
#pragma unroll
        for (int nt = 0; nt < 4; ++nt)
          acc[mt][nt] = __builtin_amdgcn_mfma_f32_16x16x32_bf16(bfr[nt], af[mt], acc[mt][nt], 0, 0, 0);
    }
  }

  if (widx < 2) {
#pragma unroll
    for (int mt = 0; mt < 4; ++mt) {
#pragma unroll
      for (int nt = 0; nt < 4; ++nt) {
        const int n = n0 + wc * 64 + nt * 16 + l16;
        const int h = n >> 6, d = n & 63;
        const float bval = (float)bias[n];
#pragma unroll
        for (int v = 0; v < 4; ++v) {
          const int m = m0 + wr * 64 + mt * 16 + quad * 4 + v;
          const int b = m >> 11, s = m & (SEQ - 1);
          float val = acc[mt][nt][v] + bval;
          // RoPE pairs (2j,2j+1) sit in adjacent lanes (d parity = lane bit 0)
          float p  = __shfl_xor(val, 1);
          float sn = (float)sp[s * 64 + (d >> 1)];
          float cs = (float)sp[s * 64 + 32 + (d >> 1)];
          val = val * cs + ((d & 1) ? p : -p) * sn;
          if (widx == 0) {
            qout[((size_t)b * SEQ + s) * HID + n] = (T)val;
          } else {
            const int hg = h - h0;
            Kws[(((size_t)b * GH + hg) * SEQ + s) * DHEAD + d] = (__bf16)val;
          }
        }
      }
    }
  } else {
#pragma unroll
    for (int mt = 0; mt < 4; ++mt) {
#pragma unroll
      for (int nt = 0; nt < 4; ++nt) {
        const int m = m0 + wr * 64 + mt * 16 + l16;    // X-row from l16 (swapped)
        const int b = m >> 11, s = m & (SEQ - 1);
#pragma unroll
        for (int v = 0; v < 4; ++v) {
          const int n = n0 + wc * 64 + nt * 16 + quad * 4 + v;
          const int h = n >> 6, d = n & 63, hg = h - h0;
          float val = acc[mt][nt][v] + (float)bias[n];
          Vws[(((size_t)b * GH + hg) * DHEAD + d) * SEQ + s] = (__bf16)val;
        }
      }
    }
  }
}

// ---------------------------------------------------------------------------
// Kernel 2: flash attention, one head group. Block = (128 q rows, b*GH+hg).
// Q read from d_out (T-typed), same slice overwritten with context at end.
// ---------------------------------------------------------------------------
#define KT 64
#define QSTR 72

template <typename T, int MODE>
__global__ __launch_bounds__(256) void attn_kernel(
    const int* __restrict__ flag,
    T* __restrict__ qo,
    const __bf16* __restrict__ Kws, const __bf16* __restrict__ Vws,
    const T* __restrict__ mask,
    int n_base, int GH)
{
  if (*flag != MODE) return;

  const int q0   = blockIdx.x * 128;
  const int by   = blockIdx.y;
  const int b    = by / GH, hg = by % GH;
  const int h    = (n_base >> 6) + hg;
  const int tid  = threadIdx.x;
  const int lane = tid & 63;
  const int wave = tid >> 6;
  const int quad = lane >> 4;
  const int l16  = lane & 15;

  __shared__ __align__(16) __bf16 Qs[128 * QSTR];
  __shared__ __align__(16) __bf16 Ks[64 * QSTR];
  __shared__ __align__(16) __bf16 Vts[64 * QSTR];
  __shared__ __align__(16) __bf16 Ps[128 * QSTR];

  T* qbase = qo + ((size_t)b * SEQ + q0) * HID + h * DHEAD;
  const __bf16* kbase = Kws + ((size_t)b * GH + hg) * SEQ * DHEAD;
  const __bf16* vbase = Vws + ((size_t)b * GH + hg) * DHEAD * SEQ;

  // ---- stage Q tile [128][64] (row stride HID in global) ----
  const int qrow = tid >> 3;        // 0..31 (+ i*32)
  const int qcb  = tid & 7;         // col block 0..7
#pragma unroll
  for (int i = 0; i < 4; ++i) {
    bf16x8 t = load8(qbase + (size_t)(qrow + i * 32) * HID + qcb * 8);
    *(bf16x8*)(Qs + (qrow + i * 32) * QSTR + qcb * 8) = t;
  }

  f32x4 o_acc[2][4];
  const f32x4 z = {0.f, 0.f, 0.f, 0.f};
#pragma unroll
  for (int i = 0; i < 2; ++i)
#pragma unroll
    for (int j = 0; j < 4; ++j) o_acc[i][j] = z;
  float m_st[2][4], l_st[2][4];
#pragma unroll
  for (int i = 0; i < 2; ++i)
#pragma unroll
    for (int v = 0; v < 4; ++v) { m_st[i][v] = -1e30f; l_st[i][v] = 0.f; }

  // ---- prefetch KV tile 0 (bf16 workspace) ----
  bf16x8 kreg[2], vreg[2];
#pragma unroll
  for (int i = 0; i < 2; ++i) {
    kreg[i] = load8(kbase + (size_t)(qrow + i * 32) * DHEAD + qcb * 8);
    vreg[i] = load8(vbase + (size_t)(qrow + i * 32) * SEQ + qcb * 8);
  }

  for (int t0 = 0; t0 < SEQ; t0 += KT) {
#pragma unroll
    for (int i = 0; i < 2; ++i) {
      *(bf16x8*)(Ks  + (qrow + i * 32) * QSTR + qcb * 8) = kreg[i];
      *(bf16x8*)(Vts + (qrow + i * 32) * QSTR + qcb * 8) = vreg[i];
    }
    __syncthreads();

    if (t0 + KT < SEQ) {
#pragma unroll
      for (int i = 0; i < 2; ++i) {
        kreg[i] = load8(kbase + (size_t)(t0 + KT + qrow + i * 32) * DHEAD + qcb * 8);
        vreg[i] = load8(vbase + (size_t)(qrow + i * 32) * SEQ + (t0 + KT) + qcb * 8);
      }
    }

    // ---- scores ----
    f32x4 sc[2][4];
#pragma unroll
    for (int mt = 0; mt < 2; ++mt)
#pragma unroll
      for (int nt = 0; nt < 4; ++nt) sc[mt][nt] = z;

#pragma unroll
    for (int ks = 0; ks < 2; ++ks) {
      bf16x8 aq[2], bk8[4];
#pragma unroll
      for (int mt = 0; mt < 2; ++mt)
        aq[mt] = *(const bf16x8*)(Qs + (wave * 32 + mt * 16 + l16) * QSTR + ks * 32 + quad * 8);
#pragma unroll
      for (int nt = 0; nt < 4; ++nt)
        bk8[nt] = *(const bf16x8*)(Ks + (nt * 16 + l16) * QSTR + ks * 32 + quad * 8);
#pragma unroll
      for (int mt = 0; mt < 2; ++mt)
#pragma unroll
        for (int nt = 0; nt < 4; ++nt)
          sc[mt][nt] = __builtin_amdgcn_mfma_f32_16x16x32_bf16(aq[mt], bk8[nt], sc[mt][nt], 0, 0, 0);
    }

    float mv[4];
#pragma unroll
    for (int nt = 0; nt < 4; ++nt)
      mv[nt] = (float)mask[b * SEQ + t0 + nt * 16 + l16];

    // ---- online softmax (wave-local rows) ----
#pragma unroll
    for (int mt = 0; mt < 2; ++mt) {
#pragma unroll
      for (int v = 0; v < 4; ++v) {
        float rmax = -1e30f;
#pragma unroll
        for (int nt = 0; nt < 4; ++nt) {
          float sv = sc[mt][nt][v] * 0.125f + mv[nt];
          sc[mt][nt][v] = sv;
          rmax = fmaxf(rmax, sv);
        }
#pragma unroll
        for (int off = 1; off < 16; off <<= 1)
          rmax = fmaxf(rmax, __shfl_xor(rmax, off));
        const float mold = m_st[mt][v];
        const float mnew = fmaxf(mold, rmax);
        const float alpha = __expf(mold - mnew);
        m_st[mt][v] = mnew;
        const int prow = wave * 32 + mt * 16 + quad * 4 + v;
        float rsum = 0.f;
#pragma unroll
        for (int nt = 0; nt < 4; ++nt) {
          float p = __expf(sc[mt][nt][v] - mnew);
          rsum += p;
          Ps[prow * QSTR + nt * 16 + l16] = (__bf16)p;
        }
#pragma unroll
        for (int off = 1; off < 16; off <<= 1)
          rsum += __shfl_xor(rsum, off);
        l_st[mt][v] = l_st[mt][v] * alpha + rsum;
#pragma unroll
        for (int nt2 = 0; nt2 < 4; ++nt2) o_acc[mt][nt2][v] *= alpha;
      }
    }
    __syncthreads();

    // ---- PV ----
#pragma unroll
    for (int ks2 = 0; ks2 < 2; ++ks2) {
      bf16x8 ap[2], bv8[4];
#pragma unroll
      for (int mt = 0; mt < 2; ++mt)
        ap[mt] = *(const bf16x8*)(Ps + (wave * 32 + mt * 16 + l16) * QSTR + ks2 * 32 + quad * 8);
#pragma unroll
      for (int nt2 = 0; nt2 < 4; ++nt2)
        bv8[nt2] = *(const bf16x8*)(Vts + (nt2 * 16 + l16) * QSTR + ks2 * 32 + quad * 8);
#pragma unroll
      for (int mt = 0; mt < 2; ++mt)
#pragma unroll
        for (int nt2 = 0; nt2 < 4; ++nt2)
          o_acc[mt][nt2] = __builtin_amdgcn_mfma_f32_16x16x32_bf16(ap[mt], bv8[nt2], o_acc[mt][nt2], 0, 0, 0);
    }
    __syncthreads();
  }

  // ---- epilogue: normalize, overwrite the Q slice with the output ----
#pragma unroll
  for (int mt = 0; mt < 2; ++mt)
#pragma unroll
    for (int nt2 = 0; nt2 < 4; ++nt2)
#pragma unroll
      for (int v = 0; v < 4; ++v) {
        const int r = wave * 32 + mt * 16 + quad * 4 + v;
        const int s = q0 + r;
        const int d = nt2 * 16 + l16;
        const float val = o_acc[mt][nt2][v] / l_st[mt][v];
        qo[((size_t)b * SEQ + s) * HID + h * DHEAD + d] = (T)val;
      }
}

// ---------------------------------------------------------------------------
extern "C" void kernel_launch(void* const* d_in, const int* in_sizes, int n_in,
                              void* d_out, int out_size, void* d_ws, size_t ws_size,
                              hipStream_t stream) {
  // ws layout: [0,256) mode flag; then K,V (always bf16)
  int* flag = (int*)d_ws;
  __bf16* Kws = (__bf16*)((char*)d_ws + 256);

  int GN;
  if      (ws_size >= 256 + (size_t)32768 * 1024) GN = 1024;  // one group
  else if (ws_size >= 256 + (size_t)32768 * 256)  GN = 256;   // 4 groups
  else                                            GN = 128;   // 8 groups
  const int GH = GN >> 6;
  const size_t els = (size_t)8192 * GN;   // elements per K (or V) group
  __bf16* Vws = Kws + els;

  detect_kernel<<<1, 64, 0, stream>>>((const uint32_t*)d_in[0], flag);

  for (int nb = 0; nb < HID; nb += GN) {
    qkv_kernel<float, 0><<<dim3(GN / 128, 64, 3), 256, 0, stream>>>(
        flag, (const float*)d_in[0],
        (const float*)d_in[3], (const float*)d_in[4],
        (const float*)d_in[5], (const float*)d_in[6],
        (const float*)d_in[7], (const float*)d_in[8],
        (const float*)d_in[2],
        (float*)d_out, Kws, Vws, nb, GH);
    qkv_kernel<__bf16, 1><<<dim3(GN / 128, 64, 3), 256, 0, stream>>>(
        flag, (const __bf16*)d_in[0],
        (const __bf16*)d_in[3], (const __bf16*)d_in[4],
        (const __bf16*)d_in[5], (const __bf16*)d_in[6],
        (const __bf16*)d_in[7], (const __bf16*)d_in[8],
        (const __bf16*)d_in[2],
        (__bf16*)d_out, Kws, Vws, nb, GH);
    attn_kernel<float, 0><<<dim3(16, BATCH * GH), 256, 0, stream>>>(
        flag, (float*)d_out, Kws, Vws, (const float*)d_in[1], nb, GH);
    attn_kernel<__bf16, 1><<<dim3(16, BATCH * GH), 256, 0, stream>>>(
        flag, (__bf16*)d_out, Kws, Vws, (const __bf16*)d_in[1], nb, GH);
  }
}